// Round 2
// baseline (6351.308 us; speedup 1.0000x reference)
//
#include <hip/hip_runtime.h>

typedef unsigned short u16;
typedef unsigned int u32;
typedef unsigned long long u64;
typedef __attribute__((ext_vector_type(8))) short short8;
typedef __attribute__((ext_vector_type(4))) float f32x4;
typedef __attribute__((ext_vector_type(4))) u32 u32x4;

#define DEV __device__ __forceinline__

DEV u16 f2b(float f) {
  u32 u = __builtin_bit_cast(u32, f);
  return (u16)((u + 0x7fffu + ((u >> 16) & 1u)) >> 16);  // RNE
}
DEV float b2f(u16 h) { u32 u = (u32)h << 16; return __builtin_bit_cast(float, u); }
DEV float sigm(float x) { return 1.0f / (1.0f + __expf(-x)); }

// ------------------------------------------------------------------
// Tiled bf16 MFMA GEMM core: C[M,N] = A[M,K] @ Bt[N,K]^T, f32 accum.
// 256 threads, 4 waves in 2x2; wave tile (BM/2 x BN/2); 16x16x32 frags.
// ------------------------------------------------------------------
template<int BM, int BN>
DEV void gemm_phase(const u16* __restrict__ A, const u16* __restrict__ Bt, int K,
                    u16* lA, u16* lB, int tid, int lane, int wm, int wn,
                    f32x4 (&acc)[BM/32][BN/32]) {
  constexpr int FM = BM / 32, FN = BN / 32;
  constexpr int CA = BM / 64, CB = BN / 64;  // 16B chunks per thread
  for (int k0 = 0; k0 < K; k0 += 32) {
    u32x4 ra[CA], rb[CB];
#pragma unroll
    for (int c2 = 0; c2 < CA; ++c2) {
      int i = c2 * 256 + tid; int row = i >> 2; int col = (i & 3) * 8;
      ra[c2] = *(const u32x4*)(A + (u64)row * K + k0 + col);
    }
#pragma unroll
    for (int c2 = 0; c2 < CB; ++c2) {
      int i = c2 * 256 + tid; int row = i >> 2; int col = (i & 3) * 8;
      rb[c2] = *(const u32x4*)(Bt + (u64)row * K + k0 + col);
    }
    __syncthreads();  // previous iter's frag reads done before overwrite
#pragma unroll
    for (int c2 = 0; c2 < CA; ++c2) { int i = c2 * 256 + tid; *(u32x4*)(lA + i * 8) = ra[c2]; }
#pragma unroll
    for (int c2 = 0; c2 < CB; ++c2) { int i = c2 * 256 + tid; *(u32x4*)(lB + i * 8) = rb[c2]; }
    __syncthreads();
    short8 af[FM], bfr[FN];
#pragma unroll
    for (int fm = 0; fm < FM; ++fm)
      af[fm] = *(const short8*)(lA + (wm * (BM / 2) + fm * 16 + (lane & 15)) * 32 + (lane >> 4) * 8);
#pragma unroll
    for (int fn = 0; fn < FN; ++fn)
      bfr[fn] = *(const short8*)(lB + (wn * (BN / 2) + fn * 16 + (lane & 15)) * 32 + (lane >> 4) * 8);
#pragma unroll
    for (int fm = 0; fm < FM; ++fm)
#pragma unroll
      for (int fn = 0; fn < FN; ++fn)
        acc[fm][fn] = __builtin_amdgcn_mfma_f32_16x16x32_bf16(af[fm], bfr[fn], acc[fm][fn], 0, 0, 0);
  }
}

// VAR: 0=att1(bf16 out,+bias)  1=preds(masked f32 to out)  2=att2|gate
//      3=h0|c0                 4=gates(+pre f32, 2-phase K) 5=pre(f32,+2 bias)
template<int BM, int BN, int VAR>
__launch_bounds__(256)
__global__ void gemm_k(const u16* __restrict__ A, const u16* __restrict__ Bt, int K,
                       const u16* __restrict__ A2, const u16* __restrict__ Bt2, int K2,
                       int N,
                       const float* __restrict__ bias1, const float* __restrict__ bias2,
                       float* __restrict__ o1, float* __restrict__ o2,
                       u16* __restrict__ ob, const float* __restrict__ pre,
                       const int* __restrict__ caplen, int t) {
  constexpr int FM = BM / 32, FN = BN / 32;
  __shared__ __align__(16) u16 lA[BM * 32];
  __shared__ __align__(16) u16 lB[BN * 32];
  const int tid = threadIdx.x, lane = tid & 63;
  const int wm = (tid >> 6) >> 1, wn = (tid >> 6) & 1;
  const int m0 = blockIdx.x * BM, n0 = blockIdx.y * BN;
  f32x4 acc[FM][FN] = {};
  gemm_phase<BM, BN>(A + (u64)m0 * K, Bt + (u64)n0 * K, K, lA, lB, tid, lane, wm, wn, acc);
  if constexpr (VAR == 4) {
    gemm_phase<BM, BN>(A2 + (u64)m0 * K2, Bt2 + (u64)n0 * K2, K2, lA, lB, tid, lane, wm, wn, acc);
  }
#pragma unroll
  for (int fm = 0; fm < FM; ++fm) {
#pragma unroll
    for (int fn = 0; fn < FN; ++fn) {
#pragma unroll
      for (int r = 0; r < 4; ++r) {
        int m = m0 + wm * (BM / 2) + fm * 16 + ((lane >> 4) << 2) + r;
        int n = n0 + wn * (BN / 2) + fn * 16 + (lane & 15);
        float v = acc[fm][fn][r];
        if constexpr (VAR == 0) {
          ob[(u64)m * 512 + n] = f2b(v + bias1[n]);
        } else if constexpr (VAR == 1) {
          if (n < N) {
            int tt = m >> 7, b = m & 127;
            float val = (tt < caplen[b] - 1) ? (v + bias1[n]) : 0.0f;
            o1[((u64)b * 51 + tt) * 18022 + n] = val;
          }
        } else if constexpr (VAR == 2) {
          if (n < 512) o1[m * 512 + n] = v + bias1[n];
          else o2[m * 2048 + (n - 512)] = sigm(v + bias2[n - 512]);
        } else if constexpr (VAR == 3) {
          if (n < 512) ob[m * 512 + n] = f2b(v + bias1[n]);
          else o2[m * 512 + (n - 512)] = v + bias2[n - 512];
        } else if constexpr (VAR == 4) {
          o1[m * 2048 + n] = v + pre[(u64)m * 2048 + n];
        } else if constexpr (VAR == 5) {
          o1[(u64)m * 2048 + n] = v + bias1[n] + bias2[n];
        }
      }
    }
  }
}

// ---------------- small prep kernels ----------------
__launch_bounds__(256)
__global__ void conv_cvt_k(u16* __restrict__ dst, const float* __restrict__ src,
                           int cols, int src_ld, int src_off) {
  int r = blockIdx.x;
  int c = blockIdx.y * 256 + threadIdx.x;
  if (c < cols) dst[(u64)r * cols + c] = f2b(src[(u64)r * src_ld + src_off + c]);
}

__launch_bounds__(256)
__global__ void transpose_cvt_k(u16* __restrict__ dst, const float* __restrict__ src, int R, int C) {
  __shared__ u16 tile[32][33];
  int c0 = blockIdx.x * 32, r0 = blockIdx.y * 32;
  int tx = threadIdx.x & 31, ty = threadIdx.x >> 5;
#pragma unroll
  for (int i = 0; i < 4; ++i) {
    int r = r0 + ty + i * 8, c = c0 + tx;
    u16 v = 0;
    if (r < R && c < C) v = f2b(src[(u64)r * C + c]);
    tile[ty + i * 8][tx] = v;
  }
  __syncthreads();
#pragma unroll
  for (int i = 0; i < 4; ++i) {
    int c = c0 + ty + i * 8, r = r0 + tx;
    if (c < C && r < R) dst[(u64)c * R + r] = tile[tx][ty + i * 8];
  }
}

__launch_bounds__(256)
__global__ void emb_gather_k(u16* __restrict__ dst, const float* __restrict__ table,
                             const int* __restrict__ caps) {
  int r = blockIdx.x;  // t*128 + b
  int c = blockIdx.y * 256 + threadIdx.x;
  int tt = r >> 7, b = r & 127;
  int tok = caps[b * 52 + tt];
  dst[(u64)r * 512 + c] = f2b(table[(u64)tok * 512 + c]);
}

__launch_bounds__(256)
__global__ void mean_k(u16* __restrict__ meanb, const u16* __restrict__ enc16) {
  int b = blockIdx.x;
  int e0 = (blockIdx.y * 256 + threadIdx.x) * 2;
  float s0 = 0.f, s1 = 0.f;
  const u16* p = enc16 + (u64)b * 196 * 2048 + e0;
  for (int pp = 0; pp < 196; ++pp) {
    u32 v = *(const u32*)(p + (u64)pp * 2048);
    s0 += b2f((u16)v); s1 += b2f((u16)(v >> 16));
  }
  const float inv = 1.0f / 196.0f;
  u32 o = (u32)f2b(s0 * inv) | ((u32)f2b(s1 * inv) << 16);
  *(u32*)(meanb + (u64)b * 2048 + e0) = o;
}

// e = relu(att1 + att2) . w_full -> softmax over p -> alpha (ws + masked out)
__launch_bounds__(256)
__global__ void alpha_k(const u16* __restrict__ att1, const float* __restrict__ att2,
                        const float* __restrict__ wfull,
                        float* __restrict__ alpha_ws, float* __restrict__ out_alpha,
                        const int* __restrict__ caplen, int t) {
  int b = blockIdx.x;
  __shared__ float s_e[196];
  __shared__ float s_red[8];
  int tid = threadIdx.x, lane = tid & 63, wave = tid >> 6;
  float a2r[8], wr[8];
  {
    const float* pa = att2 + b * 512 + lane * 8;
    const float* pw = wfull + lane * 8;
#pragma unroll
    for (int j = 0; j < 8; ++j) { a2r[j] = pa[j]; wr[j] = pw[j]; }
  }
  for (int p = wave; p < 196; p += 4) {
    const u16* row = att1 + ((u64)b * 196 + p) * 512 + lane * 8;
    u32x4 q = *(const u32x4*)row;
    float acc = 0.f;
#pragma unroll
    for (int j = 0; j < 4; ++j) {
      u32 w2 = q[j];
      float v0 = b2f((u16)w2) + a2r[2 * j];
      float v1 = b2f((u16)(w2 >> 16)) + a2r[2 * j + 1];
      acc += fmaxf(v0, 0.f) * wr[2 * j] + fmaxf(v1, 0.f) * wr[2 * j + 1];
    }
#pragma unroll
    for (int off = 32; off; off >>= 1) acc += __shfl_xor(acc, off);
    if (lane == 0) s_e[p] = acc;
  }
  __syncthreads();
  float v = (tid < 196) ? s_e[tid] : -1e30f;
  float mx = v;
#pragma unroll
  for (int off = 32; off; off >>= 1) mx = fmaxf(mx, __shfl_xor(mx, off));
  if (lane == 0) s_red[wave] = mx;
  __syncthreads();
  mx = fmaxf(fmaxf(s_red[0], s_red[1]), fmaxf(s_red[2], s_red[3]));
  float ex = (tid < 196) ? __expf(v - mx) : 0.f;
  float sm = ex;
#pragma unroll
  for (int off = 32; off; off >>= 1) sm += __shfl_xor(sm, off);
  if (lane == 0) s_red[4 + wave] = sm;
  __syncthreads();
  sm = s_red[4] + s_red[5] + s_red[6] + s_red[7];
  if (tid < 196) {
    float a = ex / sm;
    alpha_ws[b * 196 + tid] = a;
    bool act = t < caplen[b] - 1;
    out_alpha[((u64)b * 51 + t) * 196 + tid] = act ? a : 0.f;
  }
}

// y = gate * (alpha . enc)   (bf16 out)
__launch_bounds__(256)
__global__ void awe_y_k(const u16* __restrict__ enc16, const float* __restrict__ alpha_ws,
                        const float* __restrict__ gate, u16* __restrict__ y) {
  int b = blockIdx.x;
  int e0 = blockIdx.y * 1024 + threadIdx.x * 4;
  __shared__ float s_a[196];
  for (int i = threadIdx.x; i < 196; i += 256) s_a[i] = alpha_ws[b * 196 + i];
  __syncthreads();
  float acc0 = 0, acc1 = 0, acc2 = 0, acc3 = 0;
  const u16* base = enc16 + (u64)b * 196 * 2048 + e0;
#pragma unroll 4
  for (int p = 0; p < 196; ++p) {
    const u16* q = base + (u64)p * 2048;
    u32 v0 = *(const u32*)q, v1 = *(const u32*)(q + 2);
    float ap = s_a[p];
    acc0 += ap * b2f((u16)v0); acc1 += ap * b2f((u16)(v0 >> 16));
    acc2 += ap * b2f((u16)v1); acc3 += ap * b2f((u16)(v1 >> 16));
  }
  const float* g = gate + b * 2048 + e0;
  u32 w0 = (u32)f2b(acc0 * g[0]) | ((u32)f2b(acc1 * g[1]) << 16);
  u32 w1 = (u32)f2b(acc2 * g[2]) | ((u32)f2b(acc3 * g[3]) << 16);
  *(u32*)(y + (u64)b * 2048 + e0) = w0;
  *(u32*)(y + (u64)b * 2048 + e0 + 2) = w1;
}

__launch_bounds__(256)
__global__ void lstm_k(const float* __restrict__ gates, float* __restrict__ c,
                       u16* __restrict__ hbf, u16* __restrict__ hall, int t) {
  int idx = blockIdx.x * 256 + threadIdx.x;  // 65536 = 128*512
  int b = idx >> 9, d = idx & 511;
  const float* g = gates + b * 2048;
  float ig = g[d], fg = g[512 + d], gg = g[1024 + d], og = g[1536 + d];
  float cp = c[idx];
  float cn = sigm(fg) * cp + sigm(ig) * tanhf(gg);
  float hn = sigm(og) * tanhf(cn);
  c[idx] = cn;
  u16 hb = f2b(hn);
  hbf[idx] = hb;
  hall[((u64)t * 128 + b) * 512 + d] = hb;
}

// ------------------------------------------------------------------
extern "C" void kernel_launch(void* const* d_in, const int* in_sizes, int n_in,
                              void* d_out, int out_size, void* d_ws, size_t ws_size,
                              hipStream_t stream) {
  const float* enc    = (const float*)d_in[0];
  const int*   caps   = (const int*)d_in[1];
  const int*   caplen = (const int*)d_in[2];
  const float* embt   = (const float*)d_in[3];
  const float* Wenc   = (const float*)d_in[4];
  const float* benc   = (const float*)d_in[5];
  const float* Wdec   = (const float*)d_in[6];
  const float* bdec   = (const float*)d_in[7];
  const float* wfull  = (const float*)d_in[8];
  const float* Winh   = (const float*)d_in[10];
  const float* binh   = (const float*)d_in[11];
  const float* Winc   = (const float*)d_in[12];
  const float* binc   = (const float*)d_in[13];
  const float* Wfb    = (const float*)d_in[14];
  const float* bfb    = (const float*)d_in[15];
  const float* Wih    = (const float*)d_in[16];
  const float* bih    = (const float*)d_in[17];
  const float* Whh    = (const float*)d_in[18];
  const float* bhh    = (const float*)d_in[19];
  const float* Wfc    = (const float*)d_in[20];
  const float* bfc    = (const float*)d_in[21];
  float* out = (float*)d_out;
  float* out_alpha = out + 117647616ull;

  char* ws = (char*)d_ws;
  u16*   att1   = (u16*)(ws + 0);            // 25088x512 bf16
  u16*   wenc_t = (u16*)(ws + 25690112);     // 512x2048
  u16*   cat    = (u16*)(ws + 27787264);     // 4608x512: Wdec^T | Wfb^T | Whh
  u16*   wihenc = (u16*)(ws + 32505856);     // 2048x2048
  u16*   wihemb = (u16*)(ws + 40894464);     // 2048x512
  u16*   wfct   = (u16*)(ws + 42991616);     // 18022x512
  u16*   winit  = (u16*)(ws + 61446144);     // 1024x2048: Winh^T | Winc^T
  u16*   embq   = (u16*)(ws + 65640448);     // 6528x512
  float* pre    = (float*)(ws + 72325120);   // 6528x2048 f32
  u16*   hall   = (u16*)(ws + 125802496);    // 6528x512
  u16*   meanb  = (u16*)(ws + 132487168);    // 128x2048
  float* cst    = (float*)(ws + 133011456);  // 128x512 f32
  u16*   hbf    = (u16*)(ws + 133273600);    // 128x512
  float* att2   = (float*)(ws + 133404672);  // 128x512
  float* gateb  = (float*)(ws + 133666816);  // 128x2048
  float* alphaw = (float*)(ws + 134715392);  // 128x196
  u16*   ybuf   = (u16*)(ws + 134815744);    // 128x2048
  float* gates  = (float*)(ws + 135340032);  // 128x2048
  u16*   enc16  = (u16*)(ws + 136388608);    // 128x196x2048 bf16
  // total ws use: 239,149,056 B

  // ---- one-time prep ----
  transpose_cvt_k<<<dim3(16, 64), 256, 0, stream>>>(wenc_t, Wenc, 2048, 512);
  transpose_cvt_k<<<dim3(16, 16), 256, 0, stream>>>(cat, Wdec, 512, 512);
  transpose_cvt_k<<<dim3(64, 16), 256, 0, stream>>>(cat + 512 * 512, Wfb, 512, 2048);
  conv_cvt_k<<<dim3(2048, 2), 256, 0, stream>>>(cat + 2560 * 512, Whh, 512, 512, 0);
  conv_cvt_k<<<dim3(2048, 8), 256, 0, stream>>>(wihenc, Wih, 2048, 2560, 512);
  conv_cvt_k<<<dim3(2048, 2), 256, 0, stream>>>(wihemb, Wih, 512, 2560, 0);
  transpose_cvt_k<<<dim3(564, 16), 256, 0, stream>>>(wfct, Wfc, 512, 18022);
  transpose_cvt_k<<<dim3(16, 64), 256, 0, stream>>>(winit, Winh, 2048, 512);
  transpose_cvt_k<<<dim3(16, 64), 256, 0, stream>>>(winit + 512 * 2048, Winc, 2048, 512);
  conv_cvt_k<<<dim3(25088, 8), 256, 0, stream>>>(enc16, enc, 2048, 2048, 0);
  emb_gather_k<<<dim3(6528, 2), 256, 0, stream>>>(embq, embt, caps);
  mean_k<<<dim3(128, 4), 256, 0, stream>>>(meanb, enc16);
  // h0 | c0
  gemm_k<64, 64, 3><<<dim3(2, 16), 256, 0, stream>>>(
      meanb, winit, 2048, nullptr, nullptr, 0, 0, binh, binc,
      nullptr, cst, hbf, nullptr, nullptr, 0);
  // att1 = enc @ W_enc_att + b  (bf16)
  gemm_k<128, 128, 0><<<dim3(196, 4), 256, 0, stream>>>(
      enc16, wenc_t, 2048, nullptr, nullptr, 0, 0, benc, nullptr,
      nullptr, nullptr, att1, nullptr, nullptr, 0);
  // pre = emb @ W_ih_emb^T + b_ih + b_hh  (f32)
  gemm_k<128, 128, 5><<<dim3(51, 16), 256, 0, stream>>>(
      embq, wihemb, 512, nullptr, nullptr, 0, 0, bih, bhh,
      pre, nullptr, nullptr, nullptr, nullptr, 0);

  // ---- recurrent loop ----
  for (int t = 0; t < 51; ++t) {
    // att2 | gate = h @ [Wdec^T | sigmoid(Wfb^T)]
    gemm_k<64, 64, 2><<<dim3(2, 40), 256, 0, stream>>>(
        hbf, cat, 512, nullptr, nullptr, 0, 0, bdec, bfb,
        att2, gateb, nullptr, nullptr, nullptr, 0);
    alpha_k<<<128, 256, 0, stream>>>(att1, att2, wfull, alphaw, out_alpha, caplen, t);
    awe_y_k<<<dim3(128, 2), 256, 0, stream>>>(enc16, alphaw, gateb, ybuf);
    // gates = y @ Wih_enc^T + h @ Whh^T + pre_t
    gemm_k<64, 64, 4><<<dim3(2, 32), 256, 0, stream>>>(
        ybuf, wihenc, 2048, hbf, cat + 2560 * 512, 512, 0, nullptr, nullptr,
        gates, nullptr, nullptr, pre + (u64)t * 128 * 2048, nullptr, 0);
    lstm_k<<<256, 256, 0, stream>>>(gates, cst, hbf, hall, t);
  }

  // preds = h_all @ W_fc + b_fc, masked, scattered to (b,t,v)
  gemm_k<128, 128, 1><<<dim3(51, 141), 256, 0, stream>>>(
      hall, wfct, 512, nullptr, nullptr, 0, 18022, bfc, nullptr,
      out, nullptr, nullptr, nullptr, caplen, 0);
}